// Round 11
// baseline (163.332 us; speedup 1.0000x reference)
//
#include <hip/hip_runtime.h>
#include <hip/hip_bf16.h>

// Problem constants
#define NB   16
#define CIN  256
#define COUT 256
#define HH   32
#define WW   32
#define HW   1024           // 32*32
#define KK   9
#define CK   2304           // CIN*KK  (ordered k*256 + c, tap-major)

typedef __bf16 bf16x8 __attribute__((ext_vector_type(8)));
typedef float  f32x4  __attribute__((ext_vector_type(4)));

__device__ __forceinline__ unsigned short f2bf(float f) {
    unsigned int u = __float_as_uint(f);
    u += 0x7FFFu + ((u >> 16) & 1u);          // round-nearest-even
    return (unsigned short)(u >> 16);
}
__device__ __forceinline__ float bfhi(unsigned int u) {   // high bf16 -> f32
    return __uint_as_float(u & 0xFFFF0000u);
}
__device__ __forceinline__ float bflo(unsigned int u) {   // low bf16 -> f32
    return __uint_as_float(u << 16);
}

// ---------------------------------------------------------------- wconv ----
// weight fp32 [O][C][3][3] -> bf16 [O][k*256+c]  (tap-major)
__global__ __launch_bounds__(256) void wconv_kernel(const float* __restrict__ w,
                                                    unsigned short* __restrict__ wbf) {
    __shared__ float ls[CK];
    const int o = blockIdx.x;
    const float* wo = w + (size_t)o * CK;
#pragma unroll
    for (int i = threadIdx.x; i < CK; i += 256) ls[i] = wo[i];
    __syncthreads();
    unsigned short* dst = wbf + (size_t)o * CK;
#pragma unroll
    for (int i = threadIdx.x; i < CK; i += 256) {
        int k = i >> 8, c = i & 255;
        dst[i] = f2bf(ls[c * KK + k]);        // bank stride 9: conflict-free
    }
}

// ------------------------------------------------------------------- xt ----
// x fp32 [n][c][hw] -> xtb bf16 [n][hw][c]   (64x64 LDS tile transpose)
__global__ __launch_bounds__(256) void xt_kernel(const float* __restrict__ x,
                                                 unsigned short* __restrict__ xtb) {
    __shared__ float ls[64][65];
    const int c0  = blockIdx.x * 64;
    const int hw0 = blockIdx.y * 64;
    const int n   = blockIdx.z;
    const int t   = threadIdx.x;
    {
        int c = t >> 2, q = t & 3;
        const float4* base = (const float4*)(x + ((size_t)(n * CIN + c0 + c)) * HW + hw0 + q * 16);
#pragma unroll
        for (int j = 0; j < 4; ++j) {
            float4 v = base[j];
            ls[c][q * 16 + j * 4 + 0] = v.x;
            ls[c][q * 16 + j * 4 + 1] = v.y;
            ls[c][q * 16 + j * 4 + 2] = v.z;
            ls[c][q * 16 + j * 4 + 3] = v.w;
        }
    }
    __syncthreads();
    {
        int hw = t >> 2, seg = (t & 3) * 16;
        unsigned int dw[8];
#pragma unroll
        for (int j = 0; j < 8; ++j) {
            float f0 = ls[seg + 2 * j][hw];
            float f1 = ls[seg + 2 * j + 1][hw];
            dw[j] = (unsigned)f2bf(f0) | ((unsigned)f2bf(f1) << 16);
        }
        uint4* dst = (uint4*)(xtb + ((size_t)(n * HW + hw0 + hw)) * CIN + c0 + seg);
        dst[0] = *(uint4*)&dw[0];
        dst[1] = *(uint4*)&dw[4];
    }
}

// ---------------------------------------------------------------- fused ----
// SMALL-BLOCK fused kernel: 256 thr / 4 waves, tile M=128 x N=32, BK=64.
// LDS = Bs[2][32x64] bf16 = 8 KB only (64-ck rows + XOR chunk swizzle —
// the layout measured conflict-free in rounds 4-8). A-fragments load
// global->VGPR prefetched one step ahead (no tap-start stall); corners
// prefetched one step ahead. grid 1024, __launch_bounds__(256,3) ->
// 3 blocks/CU = 12 waves/CU = 3 independent barrier domains staggering
// their drains (m97-style occupancy). XCD decode pins 2 images per XCD.
__global__ __launch_bounds__(256, 3) void fused_kernel(const unsigned short* __restrict__ wbf,
                                                       const unsigned short* __restrict__ xtb,
                                                       const float* __restrict__ off,
                                                       float* __restrict__ out) {
    __shared__ unsigned short Bs[2][32 * 64];   // 8 KB

    const int tid  = threadIdx.x;
    const int wv   = tid >> 6;                // 0..3  (M position, 32 rows each)
    const int lane = tid & 63;
    const int quad = lane >> 4;
    const int l15  = lane & 15;

    const int hwl = tid >> 3;                 // 0..31  (B row this thread builds)
    const int seg = tid & 7;                  // 8-channel segment within 64

    // id bits: [0:3]=n (xcd-pinned), [4:8]=hw block (32), [9]=mh
    const int id  = blockIdx.x;
    const int n   = ((id & 7) << 1) | ((id >> 3) & 1);
    const int hw0 = ((id >> 4) & 31) * 32;
    const int mh  = id >> 9;                  // 0..1  M half

    const int hw = hw0 + hwl;
    const int h  = hw >> 5, w = hw & 31;

    const unsigned short* xb   = xtb + (size_t)n * HW * CIN;
    const float2*         offp = (const float2*)(off + ((size_t)n * HW + hw) * (2 * KK));
    const unsigned short* Abase = wbf + (size_t)(mh * 128 + wv * 32 + l15) * CK + quad * 8;

    f32x4 acc[2][2] = {};

    // issue-stream tap state
    float wgI[4];
    int   ixI[4];

    auto setup = [&](int tap) {
        float2 o = offp[tap];
        float py = (float)(h + tap / 3 - 1) + o.x;
        float px = (float)(w + tap % 3 - 1) + o.y;
        float y0f = floorf(py), x0f = floorf(px);
        float ly = py - y0f, lx = px - x0f;
        int y0 = (int)y0f, x0 = (int)x0f;
#pragma unroll
        for (int c2 = 0; c2 < 4; ++c2) {
            int yy = y0 + (c2 >> 1);
            int xx = x0 + (c2 & 1);
            float wy = (c2 >> 1) ? ly : 1.0f - ly;
            float wx = (c2 & 1) ? lx : 1.0f - lx;
            bool v = (yy >= 0) && (yy < HH) && (xx >= 0) && (xx < WW);
            wgI[c2] = v ? wy * wx : 0.0f;
            int yc = yy < 0 ? 0 : (yy > HH - 1 ? HH - 1 : yy);
            int xc = xx < 0 ? 0 : (xx > WW - 1 ? WW - 1 : xx);
            ixI[c2] = yc * WW + xc;
        }
    };

    // issue corner gathers for step t into slot (cr, wgs)
    auto issue = [&](int t, uint4 cr[4], float wgs[4]) {
        int sub = t & 3;
#pragma unroll
        for (int c2 = 0; c2 < 4; ++c2)
            cr[c2] = *(const uint4*)(xb + (size_t)ixI[c2] * CIN + sub * 64 + seg * 8);
#pragma unroll
        for (int c2 = 0; c2 < 4; ++c2) wgs[c2] = wgI[c2];
    };

    // lerp slot -> swizzled ds_write_b128 into Bs[nb]
    auto build = [&](int nb, const uint4 cr[4], const float wgs[4]) {
        unsigned u0[4], u1[4], u2[4], u3[4];
        *(uint4*)u0 = cr[0]; *(uint4*)u1 = cr[1];
        *(uint4*)u2 = cr[2]; *(uint4*)u3 = cr[3];
        unsigned dw[4];
#pragma unroll
        for (int d = 0; d < 4; ++d) {
            float2 lv;
            lv.x = wgs[0] * bflo(u0[d]) + wgs[1] * bflo(u1[d])
                 + wgs[2] * bflo(u2[d]) + wgs[3] * bflo(u3[d]);
            lv.y = wgs[0] * bfhi(u0[d]) + wgs[1] * bfhi(u1[d])
                 + wgs[2] * bfhi(u2[d]) + wgs[3] * bfhi(u3[d]);
            __hip_bfloat162 bb = __float22bfloat162_rn(lv);
            dw[d] = *(unsigned*)&bb;
        }
        *(uint4*)&Bs[nb][hwl * 64 + (seg ^ (hwl & 7)) * 8] = *(uint4*)dw;
    };

    // A-fragments for step s, direct global->VGPR
    auto loadA = [&](bf16x8 af[2][2], int s) {
        const unsigned short* p = Abase + s * 64;
#pragma unroll
        for (int mi = 0; mi < 2; ++mi)
#pragma unroll
            for (int hh = 0; hh < 2; ++hh)
                af[mi][hh] = *(const bf16x8*)(p + (size_t)mi * 16 * CK + hh * 32);
    };

    auto mfma_step = [&](int pb, const bf16x8 af[2][2]) {
        bf16x8 bfr[2][2];
#pragma unroll
        for (int ni = 0; ni < 2; ++ni)
#pragma unroll
            for (int hh = 0; hh < 2; ++hh) {
                int row = ni * 16 + l15;
                int ch  = (hh * 4 + quad) ^ (row & 7);
                bfr[ni][hh] = *(const bf16x8*)&Bs[pb][row * 64 + ch * 8];
            }
#pragma unroll
        for (int mi = 0; mi < 2; ++mi)
#pragma unroll
            for (int ni = 0; ni < 2; ++ni) {
                acc[mi][ni] = __builtin_amdgcn_mfma_f32_16x16x32_bf16(af[mi][0], bfr[ni][0], acc[mi][ni], 0, 0, 0);
                acc[mi][ni] = __builtin_amdgcn_mfma_f32_16x16x32_bf16(af[mi][1], bfr[ni][1], acc[mi][ni], 0, 0, 0);
            }
    };

    // ---- prologue: c(0)->A-slot, build Bs[0]; c(1)->B-slot; A(0)->afA
    float wgA[4], wgB[4];
    uint4 crA[4], crB[4];
    bf16x8 afA[2][2], afB[2][2];

    setup(0);
    issue(0, crA, wgA);
    loadA(afA, 0);
    build(0, crA, wgA);                        // one-time corner-latency stall
    issue(1, crB, wgB);
    __syncthreads();

    // ---- 36 steps (ck = s*64), one barrier each, 2x unrolled
    for (int sp = 0; sp < 18; ++sp) {
        const int s = sp * 2;
        // even step s: compute (Bs0, afA) | build s+1 | issue c(s+2) | A(s+1)
        if (s < 35) build(1, crB, wgB);
        if (s + 2 < 36) {
            if (((s + 2) & 3) == 0) setup((s + 2) >> 2);
            issue(s + 2, crA, wgA);
        }
        if (s < 35) loadA(afB, s + 1);
        mfma_step(0, afA);
        __syncthreads();
        // odd step s+1: compute (Bs1, afB) | build s+2 | issue c(s+3) | A(s+2)
        if (s + 1 < 35) build(0, crA, wgA);
        if (s + 3 < 36) {
            if (((s + 3) & 3) == 0) setup((s + 3) >> 2);
            issue(s + 3, crB, wgB);
        }
        if (s + 1 < 35) loadA(afA, s + 2);
        mfma_step(1, afB);
        __syncthreads();
    }

    // ---- epilogue: D layout col = lane&15, row = quad*4 + reg
    float* opnt = out + (size_t)n * COUT * HW + hw0;
#pragma unroll
    for (int mi = 0; mi < 2; ++mi)
#pragma unroll
        for (int ni = 0; ni < 2; ++ni) {
            int col = ni * 16 + l15;
#pragma unroll
            for (int rr = 0; rr < 4; ++rr) {
                int row = mh * 128 + wv * 32 + mi * 16 + quad * 4 + rr;
                opnt[(size_t)row * HW + col] = acc[mi][ni][rr];
            }
        }
}

// --------------------------------------------------------------- launch ----
extern "C" void kernel_launch(void* const* d_in, const int* in_sizes, int n_in,
                              void* d_out, int out_size, void* d_ws, size_t ws_size,
                              hipStream_t stream) {
    const float* x   = (const float*)d_in[0];   // [16][256][32][32]
    const float* off = (const float*)d_in[1];   // [16][1024][18]
    const float* wt  = (const float*)d_in[2];   // [256][256][3][3]
    float* out = (float*)d_out;                 // [16][256][32][32]

    unsigned short* wbf = (unsigned short*)d_ws;                        // 1179648 B
    unsigned short* xtb = (unsigned short*)((char*)d_ws + 1179648);     // 8388608 B

    wconv_kernel<<<256, 256, 0, stream>>>(wt, wbf);
    xt_kernel<<<dim3(4, 16, 16), 256, 0, stream>>>(x, xtb);
    fused_kernel<<<1024, 256, 0, stream>>>(wbf, xtb, off, out);
}